// Round 1
// baseline (1079.443 us; speedup 1.0000x reference)
//
#include <hip/hip_runtime.h>
#include <math.h>

#define BATCH 4096
#define SEQ   50
#define DIM   768
#define UDIM  768
#define QDIM  200

// ---------------------------------------------------------------------------
// Tiled fp32 GEMM:  out[B, N] = act( A[B, K] @ Wt[N, K]^T + bias[N] )
// 64x64 tile per block, 256 threads, 4x4 accumulators per thread,
// K staged in 16-wide chunks through LDS (pad to 68 floats: keeps 16B
// alignment for b128 reads, bank aliasing <= 2-way which is free).
// ACT: 0 = relu, 1 = tanh
// (unchanged from verified previous version)
// ---------------------------------------------------------------------------
template<int N, int K, int ACT>
__global__ __launch_bounds__(256) void pa_gemm_kernel(
    const float* __restrict__ A,
    const float* __restrict__ Wt,
    const float* __restrict__ bias,
    float* __restrict__ out)
{
    __shared__ float As[16][68];
    __shared__ float Bs[16][68];

    const int tid = threadIdx.x;
    const int tx  = tid & 15;        // 0..15  (cols)
    const int ty  = tid >> 4;        // 0..15  (rows)
    const int bm  = blockIdx.y * 64; // batch-row tile
    const int bn  = blockIdx.x * 64; // output-col tile
    const int lm  = tid >> 2;        // 0..63  load row/col
    const int lk  = (tid & 3) << 2;  // 0,4,8,12 load k offset

    float acc[4][4];
    #pragma unroll
    for (int i = 0; i < 4; i++)
        #pragma unroll
        for (int j = 0; j < 4; j++) acc[i][j] = 0.f;

    const int nk = (K + 15) / 16;
    for (int kc = 0; kc < nk; kc++) {
        const int k0 = kc * 16;
        const int ak = k0 + lk;

        float4 a4 = make_float4(0.f, 0.f, 0.f, 0.f);
        if (ak < K)  // K % 4 == 0 and ak % 4 == 0 -> full float4 in-bounds
            a4 = *(const float4*)&A[(size_t)(bm + lm) * K + ak];

        float4 b4 = make_float4(0.f, 0.f, 0.f, 0.f);
        const int nn = bn + lm;
        if (nn < N && ak < K)
            b4 = *(const float4*)&Wt[(size_t)nn * K + ak];

        __syncthreads();   // protect LDS from previous iteration's readers
        As[lk + 0][lm] = a4.x; As[lk + 1][lm] = a4.y;
        As[lk + 2][lm] = a4.z; As[lk + 3][lm] = a4.w;
        Bs[lk + 0][lm] = b4.x; Bs[lk + 1][lm] = b4.y;
        Bs[lk + 2][lm] = b4.z; Bs[lk + 3][lm] = b4.w;
        __syncthreads();

        #pragma unroll
        for (int k = 0; k < 16; k++) {
            float4 av = *(const float4*)&As[k][ty << 2];
            float4 bv = *(const float4*)&Bs[k][tx << 2];
            float am[4] = {av.x, av.y, av.z, av.w};
            float bb[4] = {bv.x, bv.y, bv.z, bv.w};
            #pragma unroll
            for (int i = 0; i < 4; i++)
                #pragma unroll
                for (int j = 0; j < 4; j++)
                    acc[i][j] = fmaf(am[i], bb[j], acc[i][j]);
        }
    }

    const int col = bn + (tx << 2);
    if (col < N) {   // N % 4 == 0 -> whole float4 valid when col < N
        #pragma unroll
        for (int i = 0; i < 4; i++) {
            const int row = bm + (ty << 2) + i;
            float v[4];
            #pragma unroll
            for (int j = 0; j < 4; j++) {
                float x = acc[i][j] + bias[col + j];
                v[j] = (ACT == 0) ? fmaxf(x, 0.f) : tanhf(x);
            }
            float4 r = make_float4(v[0], v[1], v[2], v[3]);
            *(float4*)&out[(size_t)row * N + col] = r;
        }
    }
}

// ---------------------------------------------------------------------------
// Fused attention kernel: one block per batch row b, 384 threads (6 waves).
// The entire c[b] row (50x768 f32 = 150 KB) is held in REGISTERS:
// 25 float4 per thread, index map i = tid + 384*k (coalesced for every k).
//
// Key property of the map: s = i / 192 = 2k + (tid >= 192), so every wave
// is parity-uniform in s -> the per-s dot reduction is a plain 64-lane
// shuffle reduce per k, plus a 3-way cross-wave combine in LDS.
//
// c is read from HBM exactly once; out written exactly once.
// ---------------------------------------------------------------------------
__global__ __launch_bounds__(384) void pa_attn_fused_kernel(
    const float* __restrict__ c,
    const float* __restrict__ w,
    float* __restrict__ out)
{
    __shared__ float4 wv4[DIM / 4];   // staged w row (192 float4)
    __shared__ float  ps[6][32];      // per-wave partial scores ps[wave][k]
    __shared__ float  att[64];        // softmax result (s = 0..49)

    const int b    = blockIdx.x;
    const int tid  = threadIdx.x;
    const int wave = tid >> 6;        // 0..5
    const int lane = tid & 63;
    const int col  = tid % 192;       // float4 column within a seq row
    const int half = tid / 192;       // s parity (uniform per wave)

    const float4* c4 = (const float4*)(c + (size_t)b * (SEQ * DIM));

    // stage w[b]
    if (tid < DIM / 4)
        wv4[tid] = ((const float4*)(w + (size_t)b * DIM))[tid];
    __syncthreads();

    const float4 wr = wv4[col];

    // single read of c -> registers (25 float4 = 100 VGPR per thread)
    float4 cv[25];
    #pragma unroll
    for (int k = 0; k < 25; k++)
        cv[k] = c4[tid + 384 * k];

    // partial dot per k, immediately wave-reduced (all 64 lanes share s=2k+half)
    #pragma unroll
    for (int k = 0; k < 25; k++) {
        float p = cv[k].x * wr.x + cv[k].y * wr.y
                + cv[k].z * wr.z + cv[k].w * wr.w;
        #pragma unroll
        for (int off = 32; off > 0; off >>= 1)
            p += __shfl_down(p, off, 64);
        if (lane == 0) ps[wave][k] = p;
    }
    __syncthreads();

    // softmax over S=50 (wave 0): combine 3 waves per parity, then reduce
    if (wave == 0) {
        float x = -INFINITY;
        if (lane < SEQ) {
            const int k = lane >> 1, par = lane & 1;
            x = ps[par * 3 + 0][k] + ps[par * 3 + 1][k] + ps[par * 3 + 2][k];
        }
        float m = x;
        #pragma unroll
        for (int off = 32; off > 0; off >>= 1)
            m = fmaxf(m, __shfl_down(m, off, 64));
        m = __shfl(m, 0, 64);
        float e = (lane < SEQ) ? expf(x - m) : 0.f;
        float sum = e;
        #pragma unroll
        for (int off = 32; off > 0; off >>= 1)
            sum += __shfl_down(sum, off, 64);
        sum = __shfl(sum, 0, 64);
        if (lane < SEQ) att[lane] = e / sum;
    }
    __syncthreads();

    // scale from registers and store (att[2k+half] is wave-uniform -> LDS bcast)
    float4* o4 = (float4*)(out + (size_t)b * (SEQ * DIM));
    #pragma unroll
    for (int k = 0; k < 25; k++) {
        const float a = att[2 * k + half];
        float4 v = cv[k];
        v.x *= a; v.y *= a; v.z *= a; v.w *= a;
        o4[tid + 384 * k] = v;
    }
}

extern "C" void kernel_launch(void* const* d_in, const int* in_sizes, int n_in,
                              void* d_out, int out_size, void* d_ws, size_t ws_size,
                              hipStream_t stream) {
    const float* c  = (const float*)d_in[0];   // [B, S, D]
    const float* ue = (const float*)d_in[1];   // [B, U]
    const float* W1 = (const float*)d_in[2];   // [Q, U]
    const float* b1 = (const float*)d_in[3];   // [Q]
    const float* W2 = (const float*)d_in[4];   // [D, Q]
    const float* b2 = (const float*)d_in[5];   // [D]
    float* out = (float*)d_out;

    float* q = (float*)d_ws;                   // [B, Q]  = 3.28 MB
    float* w = q + (size_t)BATCH * QDIM;       // [B, D]  = 12.6 MB

    // q = relu(ue @ W1^T + b1):  M=4096, N=200, K=768
    dim3 g1((QDIM + 63) / 64, BATCH / 64);
    pa_gemm_kernel<QDIM, UDIM, 0><<<g1, 256, 0, stream>>>(ue, W1, b1, q);

    // w = tanh(q @ W2^T + b2):   M=4096, N=768, K=200
    dim3 g2(DIM / 64, BATCH / 64);
    pa_gemm_kernel<DIM, QDIM, 1><<<g2, 256, 0, stream>>>(q, W2, b2, w);

    // fused attention + scale: c read once (register-resident), out written once
    pa_attn_fused_kernel<<<BATCH, 384, 0, stream>>>(c, w, out);
}